// Round 7
// baseline (626.506 us; speedup 1.0000x reference)
//
#include <hip/hip_runtime.h>
#include <math.h>

#define DD 128
#define NNODES 100000
#define NEDGES 600000
#define NREL 3
#define MTOT (NREL*NNODES)
#define NTILES (NNODES/16)          // 6250 row-tiles per relation
#define RT_PER_BLK 8                // 128 rows per block
#define NBLK_REL ((NTILES + RT_PER_BLK - 1)/RT_PER_BLK)   // 782

typedef __attribute__((ext_vector_type(8))) short short8;
typedef __attribute__((ext_vector_type(4))) float f32x4;

__device__ inline float bf2f(unsigned short u){ return __uint_as_float(((unsigned int)u)<<16); }
__device__ inline float bflo(unsigned int u){ return __uint_as_float(u<<16); }
__device__ inline float bfhi(unsigned int u){ return __uint_as_float(u & 0xffff0000u); }
__device__ inline unsigned short f2bf(float f){          // RNE fp32->bf16
    unsigned int i = __float_as_uint(f);
    unsigned int r = (i + 0x7fffu + ((i>>16)&1u)) >> 16;
    return (unsigned short)r;
}
__device__ inline unsigned int pack2(float lo, float hi){
    return (unsigned int)f2bf(lo) | ((unsigned int)f2bf(hi) << 16);
}
__device__ inline short8 cvt8(const float* __restrict__ p){  // 8 fp32 -> bf16x8
    f32x4 a = *(const f32x4*)p;
    f32x4 b = *(const f32x4*)(p+4);
    short8 t;
    t[0]=(short)f2bf(a[0]); t[1]=(short)f2bf(a[1]); t[2]=(short)f2bf(a[2]); t[3]=(short)f2bf(a[3]);
    t[4]=(short)f2bf(b[0]); t[5]=(short)f2bf(b[1]); t[6]=(short)f2bf(b[2]); t[7]=(short)f2bf(b[3]);
    return t;
}

// ---- K0: convert att_w1 fp32 -> bf16 -----------------------------------------
__global__ __launch_bounds__(256) void k_cvt(const float* __restrict__ in,
                                             unsigned short* __restrict__ out, int n4)
{
    int gid = blockIdx.x*256 + threadIdx.x;
    if (gid >= n4) return;
    f32x4 v = ((const f32x4*)in)[gid];
    ushort4 o;
    o.x=f2bf(v[0]); o.y=f2bf(v[1]); o.z=f2bf(v[2]); o.w=f2bf(v[3]);
    ((ushort4*)out)[gid] = o;
}

// ---- K1: f = feat @ W^T  (fp32 in -> bf16 MFMA -> bf16 out) ------------------
__global__ __launch_bounds__(256) void k_transform(
    const float* __restrict__ feat, const float* __restrict__ W,
    unsigned short* __restrict__ f_out)
{
    int wid = blockIdx.x*4 + (threadIdx.x>>6);
    if (wid >= NNODES/16) return;
    int lane = threadIdx.x & 63;
    int m = lane & 15, quad = lane >> 4;
    int n0 = wid*16;

    short8 a[4];                                   // A[m][k], k=ks*32+quad*8+j
    const float* arow = feat + (size_t)(n0+m)*DD;
    #pragma unroll
    for (int ks=0; ks<4; ++ks) a[ks] = cvt8(arow + ks*32 + quad*8);

    #pragma unroll
    for (int ct=0; ct<8; ++ct){
        f32x4 acc = {0.f,0.f,0.f,0.f};
        const float* brow = W + (size_t)(ct*16+m)*DD;   // B[k][n]=W[n][k]
        #pragma unroll
        for (int ks=0; ks<4; ++ks){
            short8 b = cvt8(brow + ks*32 + quad*8);
            acc = __builtin_amdgcn_mfma_f32_16x16x32_bf16(a[ks], b, acc, 0,0,0);
        }
        int col = ct*16 + m;
        #pragma unroll
        for (int i=0;i<4;++i)                      // C/D: col=lane&15, row=quad*4+reg
            f_out[(size_t)(n0+quad*4+i)*DD + col] = f2bf(acc[i]);
    }
}

// ---- CSR build: fused histogram over 3 relations -----------------------------
__global__ __launch_bounds__(256) void k_hist3(
    const int* __restrict__ gd, const int* __restrict__ cd, const int* __restrict__ td,
    int* __restrict__ cnt)                   // [3N]
{
    int gid = blockIdx.x*256 + threadIdx.x;
    if (gid >= NREL*NEDGES) return;
    int rel = gid / NEDGES;
    int e   = gid - rel*NEDGES;
    const int* d = (rel==0)? gd : (rel==1)? cd : td;
    atomicAdd(&cnt[rel*NNODES + d[e]], 1);
}

// ---- CSR build: two-level exclusive scan over cnt[MTOT] ----------------------
__global__ __launch_bounds__(256) void k_scan1(const int* __restrict__ cnt,
                                               int* __restrict__ offs,
                                               int* __restrict__ bsum)
{
    __shared__ int sm[256];
    int t = threadIdx.x;
    int base = blockIdx.x*1024 + t*4;
    int v[4];
    #pragma unroll
    for (int i=0;i<4;++i){ int idx=base+i; v[i] = (idx<MTOT)? cnt[idx] : 0; }
    int tot = v[0]+v[1]+v[2]+v[3];
    sm[t] = tot; __syncthreads();
    for (int off=1; off<256; off<<=1){
        int x = (t>=off)? sm[t-off] : 0;
        __syncthreads();
        sm[t] += x;
        __syncthreads();
    }
    int run = (t>0)? sm[t-1] : 0;                 // exclusive within block
    if (t==255) bsum[blockIdx.x] = sm[255];
    #pragma unroll
    for (int i=0;i<4;++i){ int idx=base+i; if (idx<MTOT) offs[idx]=run; run += v[i]; }
}

__global__ __launch_bounds__(512) void k_scan2(int* __restrict__ bsum, int nb)
{
    __shared__ int sm[512];
    int t = threadIdx.x;
    sm[t] = (t<nb)? bsum[t] : 0; __syncthreads();
    for (int off=1; off<512; off<<=1){
        int x = (t>=off)? sm[t-off] : 0;
        __syncthreads();
        sm[t] += x;
        __syncthreads();
    }
    if (t<nb) bsum[t] = (t>0)? sm[t-1] : 0;       // exclusive
}

__global__ __launch_bounds__(256) void k_scan3(int* __restrict__ offs,
                                               int* __restrict__ cursor,
                                               const int* __restrict__ bsum)
{
    int g = blockIdx.x*256 + threadIdx.x;
    if (g >= MTOT) return;
    int v = offs[g] + bsum[g>>10];
    offs[g] = v;
    cursor[g] = v;
}

// ---- CSR build: fused fill over 3 relations ----------------------------------
__global__ __launch_bounds__(256) void k_fill3(
    const int* __restrict__ gs, const int* __restrict__ gd,
    const int* __restrict__ cs, const int* __restrict__ cd,
    const int* __restrict__ ts, const int* __restrict__ td,
    const float* __restrict__ w,
    int* __restrict__ cursor,               // [3N]
    int* __restrict__ es, float* __restrict__ ewt)
{
    int gid = blockIdx.x*256 + threadIdx.x;
    if (gid >= NREL*NEDGES) return;
    int rel = gid / NEDGES;
    int e   = gid - rel*NEDGES;
    const int* s = (rel==0)? gs : (rel==1)? cs : ts;
    const int* d = (rel==0)? gd : (rel==1)? cd : td;
    int dd = d[e];
    int pos = atomicAdd(&cursor[rel*NNODES + dd], 1);
    es[pos] = s[e];
    if (rel == 2) ewt[pos - 2*NEDGES] = w[e];   // weighted relation occupies [2E,3E)
}

// ---- K2: gather-side aggregation, one 16-lane group per (rel,node) -----------
__global__ __launch_bounds__(256) void k_agg(
    const unsigned short* __restrict__ f,   // bf16 [N,128]
    const int* __restrict__ es, const float* __restrict__ ewt,
    const int* __restrict__ offs, const int* __restrict__ cnt,
    unsigned short* __restrict__ z)         // bf16 [3,N,128]: geo|cat|trans
{
    int gid = blockIdx.x*256 + threadIdx.x;
    int g = gid >> 4;                        // (rel,node) slot in [0, 3N)
    if (g >= MTOT) return;
    int c = gid & 15;                        // 8-col chunk
    int rel = g / NNODES;                    // 0 geo, 1 cat, 2 trans (weighted)
    int start = offs[g];
    int deg   = cnt[g];

    float a0=0,a1=0,a2=0,a3=0,a4=0,a5=0,a6=0,a7=0;
    int i = 0;
    for (; i+1 < deg; i += 2){               // 2 outstanding gathers
        int s0 = es[start+i], s1 = es[start+i+1];
        uint4 v0 = *(const uint4*)(f + (size_t)s0*DD + c*8);
        uint4 v1 = *(const uint4*)(f + (size_t)s1*DD + c*8);
        float w0 = (rel==2) ? ewt[start+i   - 2*NEDGES] : 1.f;
        float w1 = (rel==2) ? ewt[start+i+1 - 2*NEDGES] : 1.f;
        a0 += w0*bflo(v0.x); a1 += w0*bfhi(v0.x);
        a2 += w0*bflo(v0.y); a3 += w0*bfhi(v0.y);
        a4 += w0*bflo(v0.z); a5 += w0*bfhi(v0.z);
        a6 += w0*bflo(v0.w); a7 += w0*bfhi(v0.w);
        a0 += w1*bflo(v1.x); a1 += w1*bfhi(v1.x);
        a2 += w1*bflo(v1.y); a3 += w1*bfhi(v1.y);
        a4 += w1*bflo(v1.z); a5 += w1*bfhi(v1.z);
        a6 += w1*bflo(v1.w); a7 += w1*bfhi(v1.w);
    }
    if (i < deg){
        int s = es[start+i];
        float w = (rel==2) ? ewt[start+i - 2*NEDGES] : 1.f;
        uint4 v = *(const uint4*)(f + (size_t)s*DD + c*8);
        a0 += w*bflo(v.x); a1 += w*bfhi(v.x);
        a2 += w*bflo(v.y); a3 += w*bfhi(v.y);
        a4 += w*bflo(v.z); a5 += w*bfhi(v.z);
        a6 += w*bflo(v.w); a7 += w*bfhi(v.w);
    }
    float sc = (rel<2) ? 1.f/fmaxf((float)deg, 1.f) : 1.f;
    uint4 o;
    o.x = pack2(a0*sc, a1*sc);
    o.y = pack2(a2*sc, a3*sc);
    o.z = pack2(a4*sc, a5*sc);
    o.w = pack2(a6*sc, a7*sc);
    *(uint4*)(z + (size_t)g*DD + c*8) = o;
}

// ---- K4: w_part[rel] = sum_n w2 . tanh(W1 z_n + b1) --------------------------
// Block: 4 waves, 128 rows of one relation; z tile staged in LDS (XOR-swizzled);
// each wave owns 128 cols (8 col-tiles), B-frags in registers per col-tile.
// Fast path (781/782 blocks): rt fully unrolled -> 8 independent MFMA chains.
// tanh(x) = 1 - 2*rcp(exp2(C2*x)+1), C2 = 2*log2(e): no clamp needed.
__global__ __launch_bounds__(256) void k_att(
    const unsigned short* __restrict__ z,    // bf16 [3,N,128]
    const unsigned short* __restrict__ w1,   // bf16 [512,128]
    const float* __restrict__ bias1,         // fp32 [512]
    const float* __restrict__ wv2,           // fp32 [512]
    float* __restrict__ w_part)              // fp32 [3] (memory-relation order)
{
    __shared__ uint4 sm[RT_PER_BLK*256];     // 32 KB: unit(rt,kc,m) = rt*256+kc*16+(m^kc)
    const float C2 = 2.8853900817779268f;    // 2*log2(e)

    int rel = blockIdx.x / NBLK_REL;
    int nb  = blockIdx.x % NBLK_REL;
    int trt0 = nb * RT_PER_BLK;
    int rt_count = min(RT_PER_BLK, NTILES - trt0);
    int row0 = trt0 * 16;
    const unsigned short* zrel = z + (size_t)rel*NNODES*DD;

    int valid_rows = rt_count * 16;
    #pragma unroll
    for (int i=0; i<8; ++i){
        int u = i*256 + threadIdx.x;         // [row(128)][kc(16)]
        int row = u >> 4, kc = u & 15;
        if (row < valid_rows){
            uint4 v = *(const uint4*)(zrel + (size_t)(row0+row)*DD + kc*8);
            int rt = row >> 4, m = row & 15;
            sm[rt*256 + kc*16 + (m ^ kc)] = v;
        }
    }
    __syncthreads();

    int lane = threadIdx.x & 63;
    int wv   = threadIdx.x >> 6;             // wave 0..3 -> cols [wv*128, wv*128+128)
    int m = lane & 15, quad = lane >> 4;
    const short8* smx = (const short8*)sm;

    float s_all = 0.f;
    if (rt_count == RT_PER_BLK){
        #pragma unroll 1
        for (int ct=0; ct<8; ++ct){
            int col = (wv*8 + ct)*16 + m;
            const short8* brow = (const short8*)(w1 + (size_t)col*DD);
            short8 bf0 = brow[quad];
            short8 bf1 = brow[4 + quad];
            short8 bf2 = brow[8 + quad];
            short8 bf3 = brow[12 + quad];
            float ww  = wv2[col];
            float bbc = bias1[col] * C2;

            f32x4 sv = {0.f,0.f,0.f,0.f};
            #pragma unroll
            for (int rt=0; rt<RT_PER_BLK; ++rt){
                int base = rt*256;
                short8 a0 = smx[base + (0 + quad)*16 + (m ^ (0 + quad))];
                short8 a1 = smx[base + (4 + quad)*16 + (m ^ (4 + quad))];
                short8 a2 = smx[base + (8 + quad)*16 + (m ^ (8 + quad))];
                short8 a3 = smx[base + (12 + quad)*16 + (m ^ (12 + quad))];
                f32x4 acc = {0.f,0.f,0.f,0.f};
                acc = __builtin_amdgcn_mfma_f32_16x16x32_bf16(a0, bf0, acc, 0,0,0);
                acc = __builtin_amdgcn_mfma_f32_16x16x32_bf16(a1, bf1, acc, 0,0,0);
                acc = __builtin_amdgcn_mfma_f32_16x16x32_bf16(a2, bf2, acc, 0,0,0);
                acc = __builtin_amdgcn_mfma_f32_16x16x32_bf16(a3, bf3, acc, 0,0,0);
                #pragma unroll
                for (int i=0;i<4;++i){
                    float e = __builtin_amdgcn_exp2f(__builtin_fmaf(acc[i], C2, bbc));
                    sv[i] += __builtin_amdgcn_rcpf(e + 1.f);
                }
            }
            s_all += ww * 32.f - 2.f*ww*((sv[0]+sv[1]) + (sv[2]+sv[3]));
        }
    } else {
        #pragma unroll 1
        for (int ct=0; ct<8; ++ct){
            int col = (wv*8 + ct)*16 + m;
            const short8* brow = (const short8*)(w1 + (size_t)col*DD);
            short8 bf0 = brow[quad];
            short8 bf1 = brow[4 + quad];
            short8 bf2 = brow[8 + quad];
            short8 bf3 = brow[12 + quad];
            float ww  = wv2[col];
            float bbc = bias1[col] * C2;

            float s_r = 0.f;
            for (int rt=0; rt<rt_count; ++rt){
                int base = rt*256;
                short8 a0 = smx[base + (0 + quad)*16 + (m ^ (0 + quad))];
                short8 a1 = smx[base + (4 + quad)*16 + (m ^ (4 + quad))];
                short8 a2 = smx[base + (8 + quad)*16 + (m ^ (8 + quad))];
                short8 a3 = smx[base + (12 + quad)*16 + (m ^ (12 + quad))];
                f32x4 acc = {0.f,0.f,0.f,0.f};
                acc = __builtin_amdgcn_mfma_f32_16x16x32_bf16(a0, bf0, acc, 0,0,0);
                acc = __builtin_amdgcn_mfma_f32_16x16x32_bf16(a1, bf1, acc, 0,0,0);
                acc = __builtin_amdgcn_mfma_f32_16x16x32_bf16(a2, bf2, acc, 0,0,0);
                acc = __builtin_amdgcn_mfma_f32_16x16x32_bf16(a3, bf3, acc, 0,0,0);
                #pragma unroll
                for (int i=0;i<4;++i){
                    float e = __builtin_amdgcn_exp2f(__builtin_fmaf(acc[i], C2, bbc));
                    s_r += __builtin_amdgcn_rcpf(e + 1.f);
                }
            }
            s_all += ww * (float)(4*rt_count) - 2.f*ww*s_r;
        }
    }
    #pragma unroll
    for (int off=32; off; off>>=1) s_all += __shfl_xor(s_all, off);
    if (lane == 0) atomicAdd(&w_part[rel], s_all);
}

// ---- K5: softmax(3) + fuse + leaky relu, fp32 out ----------------------------
__global__ __launch_bounds__(256) void k_final(
    const unsigned short* __restrict__ z0, const unsigned short* __restrict__ z1,
    const unsigned short* __restrict__ z2,
    const float* __restrict__ w_part, float* __restrict__ out)
{
    int gid = blockIdx.x*256 + threadIdx.x;      // one per 4 elements
    if (gid >= NNODES*DD/4) return;
    const float invN = 1.f / (float)NNODES;
    float w0 = w_part[0]*invN, w1 = w_part[1]*invN, w2 = w_part[2]*invN;
    float mx = fmaxf(w0, fmaxf(w1, w2));
    const float LOG2E = 1.4426950408889634f;
    float e0 = __builtin_amdgcn_exp2f((w0-mx)*LOG2E);
    float e1 = __builtin_amdgcn_exp2f((w1-mx)*LOG2E);
    float e2 = __builtin_amdgcn_exp2f((w2-mx)*LOG2E);
    float inv = 1.f/(e0+e1+e2);
    float b0 = e0*inv, b1 = e1*inv, b2 = e2*inv;
    ushort4 g = ((const ushort4*)z0)[gid];
    ushort4 t = ((const ushort4*)z1)[gid];
    ushort4 c = ((const ushort4*)z2)[gid];
    f32x4 o;
    float gv[4] = {bf2f(g.x),bf2f(g.y),bf2f(g.z),bf2f(g.w)};
    float tv[4] = {bf2f(t.x),bf2f(t.y),bf2f(t.z),bf2f(t.w)};
    float cv[4] = {bf2f(c.x),bf2f(c.y),bf2f(c.z),bf2f(c.w)};
    #pragma unroll
    for (int i=0;i<4;++i){
        float x = b0*gv[i] + b1*tv[i] + b2*cv[i];
        o[i] = (x > 0.f) ? x : 0.2f*x;
    }
    ((f32x4*)out)[gid] = o;
}

extern "C" void kernel_launch(void* const* d_in, const int* in_sizes, int n_in,
                              void* d_out, int out_size, void* d_ws, size_t ws_size,
                              hipStream_t stream)
{
    const float* feat = (const float*)d_in[0];
    const float* W    = (const float*)d_in[1];
    const float* aw1  = (const float*)d_in[2];
    const float* ab1  = (const float*)d_in[3];
    const float* aw2  = (const float*)d_in[4];
    const float* tw   = (const float*)d_in[5];
    const int* geo_src   = (const int*)d_in[6];
    const int* geo_dst   = (const int*)d_in[7];
    const int* cat_src   = (const int*)d_in[8];
    const int* cat_dst   = (const int*)d_in[9];
    const int* trans_src = (const int*)d_in[10];
    const int* trans_dst = (const int*)d_in[11];

    // ws layout (~91 MB): cnt | w_part | offs | cursor | bsum | w1_bf | es | ewt | z
    char* ws = (char*)d_ws;
    int*   cnt    = (int*)ws;                        // [3N]
    float* w_part = (float*)(cnt + MTOT);            // [64]
    int*   offs   = (int*)(w_part + 64);             // [3N]
    int*   cursor = offs + MTOT;                     // [3N]
    int*   bsum   = cursor + MTOT;                   // [512]
    unsigned short* w1_bf = (unsigned short*)(bsum + 512);       // [512*128]
    int*   es     = (int*)(w1_bf + 512*DD);          // [3E]
    float* ewt    = (float*)(es + NREL*NEDGES);      // [E] (trans only)
    unsigned short* z = (unsigned short*)(ewt + NEDGES);         // [3N*128] geo|cat|trans
    unsigned short* f_bf = (unsigned short*)d_out;   // [N*128] bf16, overwritten by k_final

    // zero cnt + w_part (contiguous)
    (void)hipMemsetAsync(cnt, 0, (MTOT + 64)*sizeof(int), stream);

    k_cvt<<<64, 256, 0, stream>>>(aw1, w1_bf, 512*DD/4);
    k_transform<<<(NNODES/16 + 3)/4, 256, 0, stream>>>(feat, W, f_bf);

    int e3g = (NREL*NEDGES + 255)/256;               // 7032
    k_hist3<<<e3g, 256, 0, stream>>>(geo_dst, cat_dst, trans_dst, cnt);

    int nb = (MTOT + 1023)/1024;                     // 293
    k_scan1<<<nb, 256, 0, stream>>>(cnt, offs, bsum);
    k_scan2<<<1, 512, 0, stream>>>(bsum, nb);
    k_scan3<<<(MTOT + 255)/256, 256, 0, stream>>>(offs, cursor, bsum);

    k_fill3<<<e3g, 256, 0, stream>>>(geo_src, geo_dst, cat_src, cat_dst,
                                     trans_src, trans_dst, tw, cursor, es, ewt);

    k_agg<<<(MTOT*16 + 255)/256, 256, 0, stream>>>(f_bf, es, ewt, offs, cnt, z);

    // k_att over memory-relation order (0=geo, 1=cat, 2=trans)
    k_att<<<NREL*NBLK_REL, 256, 0, stream>>>(z, w1_bf, ab1, aw2, w_part);

    // pairing consistent with k_att: w_part[0]<->geo, [1]<->cat, [2]<->trans
    unsigned short* z_geo   = z;
    unsigned short* z_cat   = z + (size_t)NNODES*DD;
    unsigned short* z_trans = z + (size_t)2*NNODES*DD;
    int dg = (NNODES*DD/4 + 255)/256;
    k_final<<<dg, 256, 0, stream>>>(z_geo, z_cat, z_trans, w_part, (float*)d_out);
}